// Round 4
// baseline (119.292 us; speedup 1.0000x reference)
//
#include <hip/hip_runtime.h>

#define BB 8
#define NN 4096
#define CC 64
#define CENTER (32*64 + 32)
#define MS 64            // m-split: blocks per batch
#define MSL (NN/MS)      // 64 rows per k_main block
#define CUT 64           // d2 >= CUT folded into uniform far group (w <= 9.1e-4)

// ---------------- compile-time geometry ----------------
struct Geom {
    short gid[2049];     // d2 -> group id (far -> NGN)
    short g2d2[64];      // near group id -> d2
    int ng;
};

constexpr Geom makeGeom() {
    Geom t{};
    bool occ[2049] = {};
    for (int y = 0; y < 64; ++y)
        for (int x = 0; x < 64; ++x) {
            int dy = y - 32, dx = x - 32;
            occ[dy*dy + dx*dx] = true;
        }
    int g = 0;
    for (int i = 0; i < CUT; ++i) {
        if (occ[i]) { t.gid[i] = (short)g; t.g2d2[g] = (short)i; ++g; }
        else t.gid[i] = (short)-1;
    }
    t.ng = g;
    for (int i = CUT; i <= 2048; ++i) t.gid[i] = occ[i] ? (short)g : (short)-1;
    return t;
}

constexpr int NGN = makeGeom().ng;                 // near groups (29)
constexpr int GE  = 32;                            // padded group count
static_assert(NGN + 1 <= GE, "group padding");
__constant__ Geom GEOM = makeGeom();

// ---------------- workspace layout (float offsets) ----------------
constexpr int CST_WVPT = 0;                        // 4096: (wp@wv)^T  [i][c]
constexpr int CST_BVP  = 4096;                     // 64:  wp@bv
constexpr int CST_U    = 4160;                     // BB*64: wk^T q_central
constexpr int CST_T    = 4672;                     // BB
constexpr int CST_SIZE = 4736;

constexpr int OFF_CST  = 0;
constexpr int OFF_PART = CST_SIZE;                 // BB*MS*GE*CC partials
constexpr int OFF_ZP   = OFF_PART + BB*MS*GE*CC;   // BB*MS*GE
constexpr int OFF_OG   = OFF_ZP + BB*MS*GE;        // BB*GE*CC finalized

// ---------------- kernel 0: weight prep (tiny) ----------------
__global__ __launch_bounds__(256) void k_prep(
    const float* __restrict__ x,
    const float* __restrict__ wq, const float* __restrict__ bq,
    const float* __restrict__ wk, const float* __restrict__ bk,
    const float* __restrict__ wv, const float* __restrict__ bv,
    const float* __restrict__ wp,
    float* __restrict__ cst)
{
    const int tid = threadIdx.x;
    const int blk = blockIdx.x;
    if (blk < 8) {                       // per-batch u[b][i], t[b]
        __shared__ float q_s[CC];
        const int b = blk;
        if (tid < CC) {
            const float* xc = x + ((size_t)b*NN + CENTER)*CC;
            float a = bq[tid];
            for (int i = 0; i < CC; ++i) a += xc[i] * wq[tid*CC + i];
            q_s[tid] = a;
        }
        __syncthreads();
        if (tid < CC) {
            float a = 0.f;
            for (int c = 0; c < CC; ++c) a += q_s[c] * wk[c*CC + tid];
            cst[CST_U + b*CC + tid] = a;
        }
        if (tid == 64) {
            float a = 0.f;
            for (int c = 0; c < CC; ++c) a += q_s[c] * bk[c];
            cst[CST_T + b] = a;
        }
    } else if (blk < 24) {               // wvpT[i][c] = sum_j wp[c][j]*wv[j][i]
        const int idx = (blk - 8)*256 + tid;
        const int i = idx >> 6, c = idx & 63;
        float a = 0.f;
        for (int j = 0; j < CC; ++j) a += wp[c*CC + j] * wv[j*CC + i];
        cst[CST_WVPT + idx] = a;
    } else {                             // bvp = wp @ bv
        if (tid < CC) {
            float a = 0.f;
            for (int j = 0; j < CC; ++j) a += wp[tid*CC + j] * bv[j];
            cst[CST_BVP + tid] = a;
        }
    }
}

// ---------------- kernel 1: fused vp(LDS) + softmax-PV partials ----------------
#define FMA4(A, E, V) do { (A).x += (E)*(V).x; (A).y += (E)*(V).y; \
                           (A).z += (E)*(V).z; (A).w += (E)*(V).w; } while(0)

// grid MS*8 = 512: blockIdx = ms*8 + b  (b = XCD round-robin)
__global__ __launch_bounds__(256) void k_main(
    const float* __restrict__ x, const float* __restrict__ cst,
    float* __restrict__ part, float* __restrict__ zpart)
{
    __shared__ __align__(16) float vp_s[MSL*68];     // 17 KB, stride 68
    __shared__ __align__(16) float Es[MSL*36];       // 9 KB, stride 36
    __shared__ float s_s[MSL];
    __shared__ __align__(16) float4 red4[4*16*16];   // 16 KB
    __shared__ float zred[4*GE];

    const int tid = threadIdx.x;
    const int b   = blockIdx.x & 7;
    const int ms  = blockIdx.x >> 3;
    const int m0  = ms * MSL;
    const int w   = tid >> 6;
    const int l   = tid & 63;

    // ---- phase 1: vp slab into LDS (+ s by wave 0) ----
    // wave w owns c-quarter c0; readfirstlane pins it so weights use s_load
    const int c0 = __builtin_amdgcn_readfirstlane(w * 16);
    const int row = m0 + l;
    const float4* xrow4 = (const float4*)(x + ((size_t)b*NN + row)*CC);
    const float* wvpT = cst + CST_WVPT;
    const float* u    = cst + CST_U + b*CC;

    float acc1[16];
    #pragma unroll
    for (int k = 0; k < 16; ++k) acc1[k] = cst[CST_BVP + c0 + k];
    float sa = cst[CST_T + b];

    #pragma unroll
    for (int i4 = 0; i4 < 16; ++i4) {
        const float4 xi = xrow4[i4];
        if (w == 0)
            sa += xi.x*u[i4*4+0] + xi.y*u[i4*4+1] + xi.z*u[i4*4+2] + xi.w*u[i4*4+3];
        const float xv[4] = {xi.x, xi.y, xi.z, xi.w};
        #pragma unroll
        for (int ii = 0; ii < 4; ++ii) {
            const float* wr = wvpT + (i4*4 + ii)*CC + c0;   // wave-uniform -> s_load
            #pragma unroll
            for (int k = 0; k < 16; ++k) acc1[k] += xv[ii] * wr[k];
        }
    }
    if (w == 0) s_s[l] = sa * 0.125f;
    #pragma unroll
    for (int k4 = 0; k4 < 4; ++k4)
        *(float4*)&vp_s[l*68 + c0 + k4*4] =
            make_float4(acc1[k4*4+0], acc1[k4*4+1], acc1[k4*4+2], acc1[k4*4+3]);
    __syncthreads();

    // ---- phase 2a: stage Es = exp(w_g * s_m), accumulate Z ----
    const int gE = tid & 31;
    const float wg = (gE < NGN) ? __expf(1.f - sqrtf((float)GEOM.g2d2[gE])) : 0.f;
    const int mh = tid >> 5;                 // 0..7
    float zacc = 0.f;
    #pragma unroll
    for (int p = 0; p < 8; ++p) {
        const int m = mh + 8*p;
        const float e = __expf(wg * s_s[m]);
        Es[m*36 + gE] = e;
        zacc += e;
    }
    zacc += __shfl_xor(zacc, 32, 64);        // lanes l, l+32 share gE
    if (l < 32) zred[w*32 + l] = zacc;
    __syncthreads();

    // ---- phase 2b: PV accumulation, two 16-group halves ----
    const int c4 = tid & 15;
    const int mE = tid >> 4;                 // 0..15
    for (int gh = 0; gh < 2; ++gh) {
        float4 acc[16];
        #pragma unroll
        for (int g = 0; g < 16; ++g) acc[g] = make_float4(0.f, 0.f, 0.f, 0.f);
        #pragma unroll
        for (int p = 0; p < 4; ++p) {
            const int m = mE + 16*p;
            const float4 v4 = *(const float4*)&vp_s[m*68 + c4*4];
            const float4 e0 = *(const float4*)&Es[m*36 + gh*16 + 0];
            const float4 e1 = *(const float4*)&Es[m*36 + gh*16 + 4];
            const float4 e2 = *(const float4*)&Es[m*36 + gh*16 + 8];
            const float4 e3 = *(const float4*)&Es[m*36 + gh*16 + 12];
            FMA4(acc[0],  e0.x, v4); FMA4(acc[1],  e0.y, v4);
            FMA4(acc[2],  e0.z, v4); FMA4(acc[3],  e0.w, v4);
            FMA4(acc[4],  e1.x, v4); FMA4(acc[5],  e1.y, v4);
            FMA4(acc[6],  e1.z, v4); FMA4(acc[7],  e1.w, v4);
            FMA4(acc[8],  e2.x, v4); FMA4(acc[9],  e2.y, v4);
            FMA4(acc[10], e2.z, v4); FMA4(acc[11], e2.w, v4);
            FMA4(acc[12], e3.x, v4); FMA4(acc[13], e3.y, v4);
            FMA4(acc[14], e3.z, v4); FMA4(acc[15], e3.w, v4);
        }
        // reduce over mE: in-wave (mE spans 4 values per wave), then cross-wave
        #pragma unroll
        for (int g = 0; g < 16; ++g) {
            acc[g].x += __shfl_xor(acc[g].x, 16, 64);
            acc[g].y += __shfl_xor(acc[g].y, 16, 64);
            acc[g].z += __shfl_xor(acc[g].z, 16, 64);
            acc[g].w += __shfl_xor(acc[g].w, 16, 64);
            acc[g].x += __shfl_xor(acc[g].x, 32, 64);
            acc[g].y += __shfl_xor(acc[g].y, 32, 64);
            acc[g].z += __shfl_xor(acc[g].z, 32, 64);
            acc[g].w += __shfl_xor(acc[g].w, 32, 64);
        }
        if (l < 16) {
            #pragma unroll
            for (int g = 0; g < 16; ++g)
                red4[(w*16 + g)*16 + l] = acc[g];
        }
        __syncthreads();
        {
            const int g = tid >> 4, c = tid & 15;
            float4 o0 = red4[(0*16 + g)*16 + c];
            float4 o1 = red4[(1*16 + g)*16 + c];
            float4 o2 = red4[(2*16 + g)*16 + c];
            float4 o3 = red4[(3*16 + g)*16 + c];
            o0.x += o1.x + o2.x + o3.x;
            o0.y += o1.y + o2.y + o3.y;
            o0.z += o1.z + o2.z + o3.z;
            o0.w += o1.w + o2.w + o3.w;
            ((float4*)part)[(size_t)((b*MS + ms)*GE + gh*16 + g)*16 + c] = o0;
        }
        __syncthreads();
    }

    if (tid < GE) {
        float Z = zred[tid] + zred[GE + tid] + zred[2*GE + tid] + zred[3*GE + tid];
        zpart[(b*MS + ms)*GE + tid] = Z;
    }
}

// ---------------- kernel 2: reduce partials + finalize ----------------
// grid BB*GE*CC/256 = 64 blocks
__global__ __launch_bounds__(256) void k_red(
    const float* __restrict__ part, const float* __restrict__ zpart,
    const float* __restrict__ bp, float* __restrict__ og)
{
    const int idx = blockIdx.x*256 + threadIdx.x;   // [0, BB*GE*CC)
    const int bg  = idx >> 6;                       // b*GE + g
    const int b   = bg >> 5, g = bg & 31;
    const int c   = idx & 63;
    float a = 0.f, z = 0.f;
    #pragma unroll 8
    for (int ms = 0; ms < MS; ++ms) {
        a += part[(size_t)((b*MS + ms)*GE + g)*CC + c];
        z += zpart[(b*MS + ms)*GE + g];
    }
    og[(size_t)bg*CC + c] = a / z + bp[c];
}

// ---------------- kernel 3: gather ----------------
__global__ __launch_bounds__(256) void k_out(
    const float* __restrict__ og, float* __restrict__ out)
{
    const int i4 = blockIdx.x * 256 + threadIdx.x;   // [0, BB*NN*16)
    const int c4 = i4 & 15;
    const int n  = (i4 >> 4) & (NN - 1);
    const int b  = i4 >> 16;
    const int dy = (n >> 6) - 32, dx = (n & 63) - 32;
    const int g  = GEOM.gid[dy*dy + dx*dx];
    ((float4*)out)[i4] = ((const float4*)og)[(size_t)(b*GE + g)*16 + c4];
}

// ---------------- host ----------------
extern "C" void kernel_launch(void* const* d_in, const int* in_sizes, int n_in,
                              void* d_out, int out_size, void* d_ws, size_t ws_size,
                              hipStream_t stream) {
    const float* x  = (const float*)d_in[0];
    const float* wq = (const float*)d_in[1];
    const float* bq = (const float*)d_in[2];
    const float* wk = (const float*)d_in[3];
    const float* bk = (const float*)d_in[4];
    const float* wv = (const float*)d_in[5];
    const float* bv = (const float*)d_in[6];
    const float* wp = (const float*)d_in[7];
    const float* bp = (const float*)d_in[8];
    float* ws = (float*)d_ws;

    k_prep<<<25, 256, 0, stream>>>(x, wq, bq, wk, bk, wv, bv, wp, ws + OFF_CST);
    k_main<<<MS*8, 256, 0, stream>>>(x, ws + OFF_CST, ws + OFF_PART, ws + OFF_ZP);
    k_red<<<(BB*GE*CC)/256, 256, 0, stream>>>(ws + OFF_PART, ws + OFF_ZP,
                                              bp, ws + OFF_OG);
    k_out<<<2048, 256, 0, stream>>>(ws + OFF_OG, (float*)d_out);
}

// Round 5
// 103.941 us; speedup vs baseline: 1.1477x; 1.1477x over previous
//
#include <hip/hip_runtime.h>

#define BB 8
#define NN 4096
#define CC 64
#define CENTER (32*64 + 32)
#define GTILE 16
#define MS 32            // m-split factor
#define MSL (NN/MS)      // 128 m per k_attn block
#define CUT 64           // d2 >= CUT folded into uniform far group (w <= 9.1e-4)

// ---------------- compile-time geometry ----------------
struct Geom {
    short gid[2049];     // d2 -> group id (far -> NGN)
    short g2d2[64];      // near group id -> d2
    int ng;
};

constexpr Geom makeGeom() {
    Geom t{};
    bool occ[2049] = {};
    for (int y = 0; y < 64; ++y)
        for (int x = 0; x < 64; ++x) {
            int dy = y - 32, dx = x - 32;
            occ[dy*dy + dx*dx] = true;
        }
    int g = 0;
    for (int i = 0; i < CUT; ++i) {
        if (occ[i]) { t.gid[i] = (short)g; t.g2d2[g] = (short)i; ++g; }
        else t.gid[i] = (short)-1;
    }
    t.ng = g;
    for (int i = CUT; i <= 2048; ++i) t.gid[i] = occ[i] ? (short)g : (short)-1;
    return t;
}

constexpr int NGN = makeGeom().ng;                 // near groups (~29)
constexpr int NT  = (NGN + 1 + GTILE - 1) / GTILE; // g-tiles incl. far group
constexpr int GE  = NT * GTILE;                    // padded group count (32)
static_assert(NGN + 1 <= GE, "group padding");
static_assert(GE == 32, "k_red decode assumes GE=32");
static_assert(MS * 8 == 256, "blockIdx decode shift");
__constant__ Geom GEOM = makeGeom();

// ---------------- workspace layout (float offsets) ----------------
constexpr int CST_WVPT = 0;                        // 4096: (wp@wv)^T  [i][c]
constexpr int CST_BVP  = 4096;                     // 64:  wp@bv
constexpr int CST_U    = 4160;                     // BB*64: wk^T q_central
constexpr int CST_T    = 4672;                     // BB
constexpr int CST_SIZE = 4736;

constexpr int OFF_CST  = 0;
constexpr int OFF_S    = CST_SIZE;                 // BB*NN
constexpr int OFF_VP   = OFF_S + BB*NN;            // BB*NN*CC
constexpr int OFF_PART = OFF_VP + BB*NN*CC;        // BB*MS*GE*CC partials
constexpr int OFF_ZP   = OFF_PART + BB*MS*GE*CC;   // BB*MS*GE
constexpr int OFF_OG   = OFF_ZP + BB*MS*GE;        // BB*GE*CC finalized

// ---------------- kernel 0: weight prep (tiny) ----------------
__global__ __launch_bounds__(256) void k_prep(
    const float* __restrict__ x,
    const float* __restrict__ wq, const float* __restrict__ bq,
    const float* __restrict__ wk, const float* __restrict__ bk,
    const float* __restrict__ wv, const float* __restrict__ bv,
    const float* __restrict__ wp,
    float* __restrict__ cst)
{
    const int tid = threadIdx.x;
    const int blk = blockIdx.x;
    if (blk < 8) {                       // per-batch u[b][i], t[b]
        __shared__ float q_s[CC];
        const int b = blk;
        if (tid < CC) {
            const float* xc = x + ((size_t)b*NN + CENTER)*CC;
            float a = bq[tid];
            for (int i = 0; i < CC; ++i) a += xc[i] * wq[tid*CC + i];
            q_s[tid] = a;
        }
        __syncthreads();
        if (tid < CC) {
            float a = 0.f;
            for (int c = 0; c < CC; ++c) a += q_s[c] * wk[c*CC + tid];
            cst[CST_U + b*CC + tid] = a;
        }
        if (tid == 64) {
            float a = 0.f;
            for (int c = 0; c < CC; ++c) a += q_s[c] * bk[c];
            cst[CST_T + b] = a;
        }
    } else if (blk < 24) {               // wvpT[i][c] = sum_j wp[c][j]*wv[j][i]
        const int idx = (blk - 8)*256 + tid;
        const int i = idx >> 6, c = idx & 63;
        float a = 0.f;
        for (int j = 0; j < CC; ++j) a += wp[c*CC + j] * wv[j*CC + i];
        cst[CST_WVPT + idx] = a;
    } else {                             // bvp = wp @ bv
        if (tid < CC) {
            float a = 0.f;
            for (int j = 0; j < CC; ++j) a += wp[tid*CC + j] * bv[j];
            cst[CST_BVP + tid] = a;
        }
    }
}

// ---------------- kernel 1: vp + s ----------------
// grid 512: blockIdx = rowblk*4 + cq; cq (c-quarter) block-uniform -> s_loads
__global__ __launch_bounds__(256) void k_vps(
    const float* __restrict__ x, const float* __restrict__ cst,
    float* __restrict__ s_out, float* __restrict__ vp_out)
{
    const int tid = threadIdx.x;
    const int cq  = blockIdx.x & 3;
    const int row = (blockIdx.x >> 2)*256 + tid;
    const int b   = blockIdx.x >> 6;          // 64 blocks per batch

    float4 xr[16];
    const float4* x4 = (const float4*)(x + (size_t)row * CC);
    #pragma unroll
    for (int i = 0; i < 16; ++i) xr[i] = x4[i];

    if (cq == 0) {                            // s[b][m] (no max-sub: |w*s|<6)
        const float* u = cst + CST_U + b*CC;
        float sa = cst[CST_T + b];
        #pragma unroll
        for (int i4 = 0; i4 < 16; ++i4) {
            sa += xr[i4].x*u[i4*4+0] + xr[i4].y*u[i4*4+1]
                + xr[i4].z*u[i4*4+2] + xr[i4].w*u[i4*4+3];
        }
        s_out[row] = sa * 0.125f;
    }

    const int c0 = cq * 16;                   // uniform
    float4 acc[4];
    #pragma unroll
    for (int k = 0; k < 4; ++k) {
        acc[k].x = cst[CST_BVP + c0 + k*4 + 0];
        acc[k].y = cst[CST_BVP + c0 + k*4 + 1];
        acc[k].z = cst[CST_BVP + c0 + k*4 + 2];
        acc[k].w = cst[CST_BVP + c0 + k*4 + 3];
    }
    #pragma unroll
    for (int i = 0; i < 64; ++i) {
        const float xv = ((const float*)xr)[i];
        const float* wr = cst + CST_WVPT + i*CC + c0;   // uniform -> s_load
        #pragma unroll
        for (int k = 0; k < 4; ++k) {
            acc[k].x += xv * wr[k*4+0];
            acc[k].y += xv * wr[k*4+1];
            acc[k].z += xv * wr[k*4+2];
            acc[k].w += xv * wr[k*4+3];
        }
    }
    float4* vp4 = (float4*)vp_out + (size_t)row*16 + cq*4;
    #pragma unroll
    for (int k = 0; k < 4; ++k) vp4[k] = acc[k];
}

// ---------------- kernel 2: grouped softmax-PV (partials, no atomics) ----------------
#define FMA4(A, E, V) do { (A).x += (E)*(V).x; (A).y += (E)*(V).y; \
                           (A).z += (E)*(V).z; (A).w += (E)*(V).w; } while(0)

// grid NT*MS*8: blockIdx = (gt*MS + ms)*8 + b   (b = XCD round-robin)
__global__ __launch_bounds__(256) void k_attn(
    const float* __restrict__ sA, const float* __restrict__ vpA,
    float* __restrict__ part, float* __restrict__ zpart)
{
    __shared__ __align__(16) float Es[MSL*GTILE];          // 8 KB
    __shared__ __align__(16) float red[4*GTILE*GTILE*4];   // 16 KB
    __shared__ float zred[4*GTILE];
    __shared__ float w_s[GTILE];

    const int tid = threadIdx.x;
    const int b   = blockIdx.x & 7;
    const int ms  = (blockIdx.x >> 3) & (MS - 1);
    const int gt  = blockIdx.x >> 8;
    const int g0  = gt * GTILE;
    const int m0  = ms * MSL;

    if (tid < GTILE) {
        const int g = g0 + tid;
        w_s[tid] = (g < NGN) ? __expf(1.f - sqrtf((float)GEOM.g2d2[g])) : 0.f;
    }
    __syncthreads();

    const int gE = tid & 15;
    const int mE = tid >> 4;
    const float wg = w_s[gE];
    const int c4 = tid & 15;

    float zacc = 0.f;
    float4 acc[GTILE];
    #pragma unroll
    for (int g = 0; g < GTILE; ++g) acc[g] = make_float4(0.f, 0.f, 0.f, 0.f);

    const float* s_row = sA + b*NN + m0;
    const float4* vp4  = (const float4*)vpA + ((size_t)b*NN + m0)*16;
    const float4* E4   = (const float4*)Es;

    #pragma unroll
    for (int p = 0; p < MSL/16; ++p) {          // stage exp(w*s)
        const int ml = mE + 16*p;
        const float e = __expf(wg * s_row[ml]);
        Es[ml*GTILE + gE] = e;
        zacc += e;
    }
    __syncthreads();
    #pragma unroll
    for (int p = 0; p < MSL/16; ++p) {
        const int ml = mE + 16*p;
        const float4 v4 = vp4[(size_t)ml*16 + c4];
        float4 e4;
        e4 = E4[ml*4 + 0];
        FMA4(acc[0],  e4.x, v4); FMA4(acc[1],  e4.y, v4);
        FMA4(acc[2],  e4.z, v4); FMA4(acc[3],  e4.w, v4);
        e4 = E4[ml*4 + 1];
        FMA4(acc[4],  e4.x, v4); FMA4(acc[5],  e4.y, v4);
        FMA4(acc[6],  e4.z, v4); FMA4(acc[7],  e4.w, v4);
        e4 = E4[ml*4 + 2];
        FMA4(acc[8],  e4.x, v4); FMA4(acc[9],  e4.y, v4);
        FMA4(acc[10], e4.z, v4); FMA4(acc[11], e4.w, v4);
        e4 = E4[ml*4 + 3];
        FMA4(acc[12], e4.x, v4); FMA4(acc[13], e4.y, v4);
        FMA4(acc[14], e4.z, v4); FMA4(acc[15], e4.w, v4);
    }
    __syncthreads();

    // reduce over mE: in-wave butterfly, cross-wave via LDS, one partial store
    const int l  = tid & 63;
    const int wv = tid >> 6;
    #pragma unroll
    for (int g = 0; g < GTILE; ++g) {
        acc[g].x += __shfl_xor(acc[g].x, 16, 64);
        acc[g].y += __shfl_xor(acc[g].y, 16, 64);
        acc[g].z += __shfl_xor(acc[g].z, 16, 64);
        acc[g].w += __shfl_xor(acc[g].w, 16, 64);
        acc[g].x += __shfl_xor(acc[g].x, 32, 64);
        acc[g].y += __shfl_xor(acc[g].y, 32, 64);
        acc[g].z += __shfl_xor(acc[g].z, 32, 64);
        acc[g].w += __shfl_xor(acc[g].w, 32, 64);
    }
    zacc += __shfl_xor(zacc, 16, 64);
    zacc += __shfl_xor(zacc, 32, 64);

    float4* red4 = (float4*)red;
    if (l < 16) {
        #pragma unroll
        for (int g = 0; g < GTILE; ++g)
            red4[(wv*GTILE + g)*GTILE + l] = acc[g];
        zred[wv*16 + l] = zacc;
    }
    __syncthreads();

    {
        const int g = tid >> 4, c = tid & 15;
        float4 o0 = red4[(0*GTILE + g)*GTILE + c];
        float4 o1 = red4[(1*GTILE + g)*GTILE + c];
        float4 o2 = red4[(2*GTILE + g)*GTILE + c];
        float4 o3 = red4[(3*GTILE + g)*GTILE + c];
        o0.x += o1.x + o2.x + o3.x;
        o0.y += o1.y + o2.y + o3.y;
        o0.z += o1.z + o2.z + o3.z;
        o0.w += o1.w + o2.w + o3.w;
        ((float4*)part)[(size_t)((b*MS + ms)*GE + g0 + g)*16 + c] = o0;
        if (tid < 16) {
            float Zg = zred[tid] + zred[16+tid] + zred[32+tid] + zred[48+tid];
            zpart[(b*MS + ms)*GE + g0 + tid] = Zg;
        }
    }
}

// ---------------- kernel 3: reduce partials + finalize ----------------
// grid BB*GE = 256 blocks (1/CU); block = (b,g); threads split ms 4-way
__global__ __launch_bounds__(256) void k_red(
    const float* __restrict__ part, const float* __restrict__ zpart,
    const float* __restrict__ bp, float* __restrict__ og)
{
    __shared__ float ared[4*CC];
    __shared__ float zr[4];

    const int tid = threadIdx.x;
    const int bg  = blockIdx.x;                 // b*GE + g
    const int b   = bg >> 5, g = bg & 31;
    const int q   = tid >> 6;                   // ms quarter 0..3
    const int c   = tid & 63;

    float a = 0.f, z = 0.f;
    #pragma unroll
    for (int j = 0; j < MS/4; ++j) {
        const int ms = q*(MS/4) + j;
        a += part[(size_t)((b*MS + ms)*GE + g)*CC + c];
        z += zpart[(b*MS + ms)*GE + g];
    }
    ared[q*CC + c] = a;
    if (c == 0) zr[q] = z;
    __syncthreads();
    if (tid < CC) {
        const float at = ared[tid] + ared[CC + tid] + ared[2*CC + tid] + ared[3*CC + tid];
        const float zt = zr[0] + zr[1] + zr[2] + zr[3];
        og[(size_t)bg*CC + tid] = at / zt + bp[tid];
    }
}

// ---------------- kernel 4: gather ----------------
__global__ __launch_bounds__(256) void k_out(
    const float* __restrict__ og, float* __restrict__ out)
{
    const int i4 = blockIdx.x * 256 + threadIdx.x;   // [0, BB*NN*16)
    const int c4 = i4 & 15;
    const int n  = (i4 >> 4) & (NN - 1);
    const int b  = i4 >> 16;
    const int dy = (n >> 6) - 32, dx = (n & 63) - 32;
    const int g  = GEOM.gid[dy*dy + dx*dx];
    ((float4*)out)[i4] = ((const float4*)og)[(size_t)(b*GE + g)*16 + c4];
}

// ---------------- host ----------------
extern "C" void kernel_launch(void* const* d_in, const int* in_sizes, int n_in,
                              void* d_out, int out_size, void* d_ws, size_t ws_size,
                              hipStream_t stream) {
    const float* x  = (const float*)d_in[0];
    const float* wq = (const float*)d_in[1];
    const float* bq = (const float*)d_in[2];
    const float* wk = (const float*)d_in[3];
    const float* bk = (const float*)d_in[4];
    const float* wv = (const float*)d_in[5];
    const float* bv = (const float*)d_in[6];
    const float* wp = (const float*)d_in[7];
    const float* bp = (const float*)d_in[8];
    float* ws = (float*)d_ws;

    k_prep<<<25, 256, 0, stream>>>(x, wq, bq, wk, bk, wv, bv, wp, ws + OFF_CST);
    k_vps<<<512, 256, 0, stream>>>(x, ws + OFF_CST, ws + OFF_S, ws + OFF_VP);
    k_attn<<<NT*MS*8, 256, 0, stream>>>(ws + OFF_S, ws + OFF_VP,
                                        ws + OFF_PART, ws + OFF_ZP);
    k_red<<<BB*GE, 256, 0, stream>>>(ws + OFF_PART, ws + OFF_ZP,
                                     bp, ws + OFF_OG);
    k_out<<<2048, 256, 0, stream>>>(ws + OFF_OG, (float*)d_out);
}